// Round 14
// baseline (188.132 us; speedup 1.0000x reference)
//
#include <hip/hip_runtime.h>

// SNNLinear, exact-trajectory i8-digit MFMA. Round 14 = R13 bit-identical,
// MEASUREMENT ROUND: prepass launched 5x (idempotent — same bytes written
// each time). dur_us_R14 - dur_us_R13 = 4 x (prepass + launch overhead).
// This splits the ~93us non-GEMM time into {prepass, scan+fixed} decisively;
// R15 will act on the measured split.
// Math proven R3-R13 (bit-identical): Wq=round(W*2^36), 5 balanced base-256
// i8 digit planes; mfma_i32_16x16x64_i8 exact; i64 Horner -> f64 du ->
// f32 hi (ss region) + f16 lo*2^12 (ws). Scan in f64.
// Outputs: ss[100,64,1024] | mem_out[64,1024] | hat_s[64,1024]
// ws: [0,6.55M) A8 ; [6.55M,11.8M) Bt ; [11.8M,24.9M) Lo

typedef __attribute__((ext_vector_type(4))) int int4v;

#define T_STEPS 100
#define BO 65536
#define K_DIM 1024
#define A8_OFF 0
#define BT_OFF 6553600
#define LO_OFF 11796480

// ---- prepass, fragment-coalesced: wave = one (m16|n16, k64) tile ----
__global__ __launch_bounds__(256)
void prepass(const float* __restrict__ S, const float* __restrict__ W,
             signed char* __restrict__ A8, signed char* __restrict__ Bt) {
    const int wave = blockIdx.x * 4 + (threadIdx.x >> 6);  // 0..7423
    const int lane = threadIdx.x & 63;
    const int r16 = lane & 15, quad = lane >> 4;

    if (wave < 6400) {
        // spikes -> A8: tile (m16, k64); lane writes frag slot lane.
        const int m16 = wave >> 4, k64 = wave & 15;
        const int m = m16 * 16 + r16;
        const float* sp = S + (size_t)m * K_DIM + k64 * 64 + quad * 16;
        const float4 s0 = *(const float4*)(sp);
        const float4 s1 = *(const float4*)(sp + 4);
        const float4 s2 = *(const float4*)(sp + 8);
        const float4 s3 = *(const float4*)(sp + 12);
        const float sv[16] = {s0.x,s0.y,s0.z,s0.w, s1.x,s1.y,s1.z,s1.w,
                              s2.x,s2.y,s2.z,s2.w, s3.x,s3.y,s3.z,s3.w};
        union { signed char c[16]; int4v v; } u;
#pragma unroll
        for (int e = 0; e < 16; ++e) u.c[e] = (signed char)sv[e];   // exact 0/1
        *(int4v*)(A8 + ((size_t)(m16 * 16 + k64) * 1024) + lane * 16) = u.v;
    } else {
        // W -> Bt: tile (n16, k64); lane writes frag slot lane, 5 planes.
        const int t2 = wave - 6400;                 // 0..1023
        const int n16 = t2 >> 4, k64 = t2 & 15;
        const int n = n16 * 16 + r16;
        const float* wp = W + (size_t)n * K_DIM + k64 * 64 + quad * 16;
        const float4 w0 = *(const float4*)(wp);
        const float4 w1 = *(const float4*)(wp + 4);
        const float4 w2 = *(const float4*)(wp + 8);
        const float4 w3 = *(const float4*)(wp + 12);
        const float wv[16] = {w0.x,w0.y,w0.z,w0.w, w1.x,w1.y,w1.z,w1.w,
                              w2.x,w2.y,w2.z,w2.w, w3.x,w3.y,w3.z,w3.w};
        union { signed char c[16]; int4v v; } u[5];
#pragma unroll
        for (int e = 0; e < 16; ++e) {
            long long q = llrint((double)wv[e] * 0x1p36);   // |q| < 2^39
#pragma unroll
            for (int p = 0; p < 4; ++p) {
                const int d = (int)(((q + 128) & 255) - 128);  // [-128,127]
                u[p].c[e] = (signed char)d;
                q = (q - d) >> 8;                              // exact
            }
            u[4].c[e] = (signed char)q;                        // |d4| <= ~115
        }
        signed char* base = Bt + (size_t)(n16 * 16 + k64) * 5 * 1024 + lane * 16;
#pragma unroll
        for (int p = 0; p < 5; ++p)
            *(int4v*)(base + (size_t)p * 1024) = u[p].v;
    }
}

// ---- GEMM (R11/R13 verbatim): block 128m x 32n, 4 waves, no LDS/barriers ----
__global__ __launch_bounds__(256)
void gemm_i8(const signed char* __restrict__ A8,
             const signed char* __restrict__ Bt,
             const float* __restrict__ bias,
             float* __restrict__ Chi,          // hi -> ss region
             _Float16* __restrict__ Lo) {      // lo*4096 residual
    const int bid = blockIdx.x;                // 0..1599
    const int xcd = bid & 7;
    const int t_  = bid >> 3;
    const int cu  = t_ & 31;
    const int rnd = t_ >> 5;
    const int bn = (xcd << 2) | (cu & 3);      // 0..31
    const int bm = (cu >> 2) + (rnd << 3);     // 0..49

    const int tid = threadIdx.x;
    const int lane = tid & 63, wid = tid >> 6;
    const int wm = wid >> 1, wn = wid & 1;
    const int quad = lane >> 4, r16 = lane & 15;
    const int mgb = bm * 8 + wm * 4;
    const int ng  = bn * 2 + wn;

    const signed char* Ab = A8 + (size_t)mgb * 16384 + (size_t)lane * 16;
    const signed char* Bb = Bt + (size_t)ng * 81920 + (size_t)lane * 16;

    int4v a0[4], a1[4], b0[5], b1[5];
    int4v acc[4][5] = {};

    auto loadA = [&](int kt, int4v* a) {
#pragma unroll
        for (int i = 0; i < 4; ++i)
            a[i] = *(const int4v*)(Ab + (size_t)(i * 16 + kt) * 1024);
    };
    auto loadB = [&](int kt, int4v* b) {
#pragma unroll
        for (int p = 0; p < 5; ++p)
            b[p] = *(const int4v*)(Bb + (size_t)(kt * 5 + p) * 1024);
    };
    auto mf = [&](const int4v* a, const int4v* b) {
#pragma unroll
        for (int p = 0; p < 5; ++p)
#pragma unroll
            for (int i = 0; i < 4; ++i)
                acc[i][p] = __builtin_amdgcn_mfma_i32_16x16x64_i8(
                    a[i], b[p], acc[i][p], 0, 0, 0);
    };

    loadA(0, a0); loadB(0, b0);
    loadA(1, a1); loadB(1, b1);
    for (int kt = 0; kt < 16; kt += 2) {
        mf(a0, b0);
        if (kt + 2 < 16) { loadA(kt + 2, a0); loadB(kt + 2, b0); }
        mf(a1, b1);
        if (kt + 3 < 16) { loadA(kt + 3, a1); loadB(kt + 3, b1); }
    }

    const int n_g = bn * 32 + wn * 16 + r16;
    const double bd = (double)bias[n_g];
#pragma unroll
    for (int i = 0; i < 4; ++i)
#pragma unroll
        for (int e = 0; e < 4; ++e) {
            long long t = (long long)acc[i][4][e];
            t = t * 256 + (long long)acc[i][3][e];
            t = t * 256 + (long long)acc[i][2][e];
            t = t * 256 + (long long)acc[i][1][e];
            t = t * 256 + (long long)acc[i][0][e];   // exact, |t| < 2^50
            const double du = (double)t * 0x1p-36 + bd;
            const float hi = (float)du;
            const float lo = (float)(du - (double)hi);
            const size_t m_g = (size_t)(bm * 128 + wm * 64 + i * 16 + quad * 4 + e);
            const size_t off = m_g * 1024 + n_g;
            Chi[off] = hi;
            Lo[off] = (_Float16)(lo * 4096.0f);
        }
}

// ---- membrane scan (R13 verbatim): f64, 4-slot ring, 3 groups ahead ----
__global__ __launch_bounds__(256)
void snn_scan(float* __restrict__ out, const _Float16* __restrict__ lo,
              const float* __restrict__ mem0) {
    const int bo = blockIdx.x * 256 + threadIdx.x;
    double m = (double)mem0[bo];
    double cnt = 0.0;
    float h[4][4], l[4][4];
#pragma unroll
    for (int s = 0; s < 3; ++s)
#pragma unroll
        for (int u = 0; u < 4; ++u) {
            const size_t idx = (size_t)(s * 4 + u) * BO + bo;
            h[s][u] = out[idx];
            l[s][u] = (float)lo[idx];
        }
#pragma unroll
    for (int g = 0; g < 25; ++g) {
        const int cs = g & 3, ps = (g + 3) & 3;
        if (g + 3 < 25) {
#pragma unroll
            for (int u = 0; u < 4; ++u) {
                const size_t idx = (size_t)((g + 3) * 4 + u) * BO + bo;
                h[ps][u] = out[idx];
                l[ps][u] = (float)lo[idx];
            }
        }
#pragma unroll
        for (int u = 0; u < 4; ++u) {
            const double du = (double)h[cs][u] + (double)l[cs][u] * 0x1p-12;
            m += du;
            const double s = (m > 15.0) ? 1.0 : 0.0;
            m = fmin(fmax(m, 0.0), 15.0);
            out[(size_t)(g * 4 + u) * BO + bo] = (float)s;
            cnt += s;
            m -= m * s;
        }
    }
    out[(size_t)T_STEPS * BO + bo] = (float)m;
    out[(size_t)(T_STEPS + 1) * BO + bo] = (float)(cnt * 0.01);
}

extern "C" void kernel_launch(void* const* d_in, const int* in_sizes, int n_in,
                              void* d_out, int out_size, void* d_ws, size_t ws_size,
                              hipStream_t stream) {
    const float* spikes = (const float*)d_in[0];  // [100,64,1024]
    const float* mem    = (const float*)d_in[1];  // [64,1024]
    // d_in[2] = hat_spikes: dead in forward
    const float* W      = (const float*)d_in[3];  // [1024,1024]
    const float* b      = (const float*)d_in[4];  // [1024]
    float* out = (float*)d_out;
    signed char* A8 = (signed char*)d_ws + A8_OFF;
    signed char* Bt = (signed char*)d_ws + BT_OFF;
    _Float16*    Lo = (_Float16*)((char*)d_ws + LO_OFF);

    // MEASUREMENT: 5 idempotent prepass launches (4 extra).
    // dur_R14 - dur_R13 = 4 x (prepass + launch overhead).
    for (int r = 0; r < 5; ++r)
        prepass<<<dim3(1856), 256, 0, stream>>>(spikes, W, A8, Bt);
    gemm_i8<<<dim3(1600), 256, 0, stream>>>(A8, Bt, b, out, Lo);
    snn_scan<<<dim3(BO / 256), 256, 0, stream>>>(out, Lo, mem);
}

// Round 15
// 161.932 us; speedup vs baseline: 1.1618x; 1.1618x over previous
//
#include <hip/hip_runtime.h>

// SNNLinear, exact-trajectory i8-digit MFMA. Round 15 = R13 with the GEMM
// wave-tile halved for occupancy:
//   - wave tile 32m x 16n x 5 planes (acc 40 + pipeline 56 + misc ~ 120 regs),
//     __launch_bounds__(256,4) -> 4 waves/SIMD (R13's 64m tile needed ~180
//     regs incl. AGPR-acc -> 2 waves/SIMD; occupancy, not traffic, is the
//     hypothesized binding constraint -- traffic fixes R8/R11 were null).
//   - block 64m x 32n (4 waves 2m x 2n), grid (32,100) bn-fastest (XCD
//     locality proven in R8: FETCH halved).
// Arithmetic bit-identical (exact integer accums, order-free): Wq=round
// (W*2^36), 5 balanced base-256 i8 planes; mfma_i32_16x16x64_i8; i64 Horner
// -> f64 du -> f32 hi (ss region) + f16 lo*2^12 (ws). Scan f64 (R13 verbatim).
// Fixed harness cost measured ~70us (R14 x5-prepass experiment + R7/R12 gaps);
// kernel budget: gemm 58.7 + scan ~13 + prepass ~9.
// Outputs: ss[100,64,1024] | mem_out[64,1024] | hat_s[64,1024]
// ws: [0,6.55M) A8 ; [6.55M,11.8M) Bt ; [11.8M,24.9M) Lo

typedef __attribute__((ext_vector_type(4))) int int4v;

#define T_STEPS 100
#define BO 65536
#define K_DIM 1024
#define A8_OFF 0
#define BT_OFF 6553600
#define LO_OFF 11796480

// ---- prepass (R13 verbatim), fragment-coalesced ----
__global__ __launch_bounds__(256)
void prepass(const float* __restrict__ S, const float* __restrict__ W,
             signed char* __restrict__ A8, signed char* __restrict__ Bt) {
    const int wave = blockIdx.x * 4 + (threadIdx.x >> 6);  // 0..7423
    const int lane = threadIdx.x & 63;
    const int r16 = lane & 15, quad = lane >> 4;

    if (wave < 6400) {
        const int m16 = wave >> 4, k64 = wave & 15;
        const int m = m16 * 16 + r16;
        const float* sp = S + (size_t)m * K_DIM + k64 * 64 + quad * 16;
        const float4 s0 = *(const float4*)(sp);
        const float4 s1 = *(const float4*)(sp + 4);
        const float4 s2 = *(const float4*)(sp + 8);
        const float4 s3 = *(const float4*)(sp + 12);
        const float sv[16] = {s0.x,s0.y,s0.z,s0.w, s1.x,s1.y,s1.z,s1.w,
                              s2.x,s2.y,s2.z,s2.w, s3.x,s3.y,s3.z,s3.w};
        union { signed char c[16]; int4v v; } u;
#pragma unroll
        for (int e = 0; e < 16; ++e) u.c[e] = (signed char)sv[e];   // exact 0/1
        *(int4v*)(A8 + ((size_t)(m16 * 16 + k64) * 1024) + lane * 16) = u.v;
    } else {
        const int t2 = wave - 6400;                 // 0..1023
        const int n16 = t2 >> 4, k64 = t2 & 15;
        const int n = n16 * 16 + r16;
        const float* wp = W + (size_t)n * K_DIM + k64 * 64 + quad * 16;
        const float4 w0 = *(const float4*)(wp);
        const float4 w1 = *(const float4*)(wp + 4);
        const float4 w2 = *(const float4*)(wp + 8);
        const float4 w3 = *(const float4*)(wp + 12);
        const float wv[16] = {w0.x,w0.y,w0.z,w0.w, w1.x,w1.y,w1.z,w1.w,
                              w2.x,w2.y,w2.z,w2.w, w3.x,w3.y,w3.z,w3.w};
        union { signed char c[16]; int4v v; } u[5];
#pragma unroll
        for (int e = 0; e < 16; ++e) {
            long long q = llrint((double)wv[e] * 0x1p36);   // |q| < 2^39
#pragma unroll
            for (int p = 0; p < 4; ++p) {
                const int d = (int)(((q + 128) & 255) - 128);  // [-128,127]
                u[p].c[e] = (signed char)d;
                q = (q - d) >> 8;                              // exact
            }
            u[4].c[e] = (signed char)q;                        // |d4| <= ~115
        }
        signed char* base = Bt + (size_t)(n16 * 16 + k64) * 5 * 1024 + lane * 16;
#pragma unroll
        for (int p = 0; p < 5; ++p)
            *(int4v*)(base + (size_t)p * 1024) = u[p].v;
    }
}

// ---- GEMM: block 64m x 32n = 4 waves (2m x 2n), wave 32m x 16n x 5 planes.
// No LDS/barriers; 2-deep register pipeline; 4 waves/SIMD via launch bounds. ----
__global__ __launch_bounds__(256, 4)
void gemm_i8(const signed char* __restrict__ A8,
             const signed char* __restrict__ Bt,
             const float* __restrict__ bias,
             float* __restrict__ Chi,          // hi -> ss region
             _Float16* __restrict__ Lo) {      // lo*4096 residual
    const int bn = blockIdx.x;                 // 0..31  (fastest: XCD locality)
    const int bm = blockIdx.y;                 // 0..99
    const int tid = threadIdx.x;
    const int lane = tid & 63, wid = tid >> 6;
    const int wm = wid >> 1, wn = wid & 1;
    const int quad = lane >> 4, r16 = lane & 15;
    const int mgb = bm * 4 + wm * 2;           // first m16 group of this wave
    const int ng  = bn * 2 + wn;               // n16 group

    const signed char* Ab = A8 + (size_t)mgb * 16384 + (size_t)lane * 16;
    const signed char* Bb = Bt + (size_t)ng * 81920 + (size_t)lane * 16;

    int4v a0[2], a1[2], b0[5], b1[5];
    int4v acc[2][5] = {};

    auto loadA = [&](int kt, int4v* a) {
#pragma unroll
        for (int i = 0; i < 2; ++i)
            a[i] = *(const int4v*)(Ab + (size_t)(i * 16 + kt) * 1024);
    };
    auto loadB = [&](int kt, int4v* b) {
#pragma unroll
        for (int p = 0; p < 5; ++p)
            b[p] = *(const int4v*)(Bb + (size_t)(kt * 5 + p) * 1024);
    };
    auto mf = [&](const int4v* a, const int4v* b) {
#pragma unroll
        for (int p = 0; p < 5; ++p)
#pragma unroll
            for (int i = 0; i < 2; ++i)
                acc[i][p] = __builtin_amdgcn_mfma_i32_16x16x64_i8(
                    a[i], b[p], acc[i][p], 0, 0, 0);
    };

    loadA(0, a0); loadB(0, b0);
    loadA(1, a1); loadB(1, b1);
    for (int kt = 0; kt < 16; kt += 2) {
        mf(a0, b0);
        if (kt + 2 < 16) { loadA(kt + 2, a0); loadB(kt + 2, b0); }
        mf(a1, b1);
        if (kt + 3 < 16) { loadA(kt + 3, a1); loadB(kt + 3, b1); }
    }

    // epilogue: exact i64 Horner recombine -> f64 du -> hi/lo store
    const int n_g = bn * 32 + wn * 16 + r16;
    const double bd = (double)bias[n_g];
#pragma unroll
    for (int i = 0; i < 2; ++i)
#pragma unroll
        for (int e = 0; e < 4; ++e) {
            long long t = (long long)acc[i][4][e];
            t = t * 256 + (long long)acc[i][3][e];
            t = t * 256 + (long long)acc[i][2][e];
            t = t * 256 + (long long)acc[i][1][e];
            t = t * 256 + (long long)acc[i][0][e];   // exact, |t| < 2^50
            const double du = (double)t * 0x1p-36 + bd;
            const float hi = (float)du;
            const float lo = (float)(du - (double)hi);
            const size_t m_g = (size_t)(bm * 64 + wm * 32 + i * 16 + quad * 4 + e);
            const size_t off = m_g * 1024 + n_g;
            Chi[off] = hi;
            Lo[off] = (_Float16)(lo * 4096.0f);
        }
}

// ---- membrane scan (R13 verbatim): f64, 4-slot ring, 3 groups ahead ----
__global__ __launch_bounds__(256)
void snn_scan(float* __restrict__ out, const _Float16* __restrict__ lo,
              const float* __restrict__ mem0) {
    const int bo = blockIdx.x * 256 + threadIdx.x;
    double m = (double)mem0[bo];
    double cnt = 0.0;
    float h[4][4], l[4][4];
#pragma unroll
    for (int s = 0; s < 3; ++s)
#pragma unroll
        for (int u = 0; u < 4; ++u) {
            const size_t idx = (size_t)(s * 4 + u) * BO + bo;
            h[s][u] = out[idx];
            l[s][u] = (float)lo[idx];
        }
#pragma unroll
    for (int g = 0; g < 25; ++g) {
        const int cs = g & 3, ps = (g + 3) & 3;
        if (g + 3 < 25) {
#pragma unroll
            for (int u = 0; u < 4; ++u) {
                const size_t idx = (size_t)((g + 3) * 4 + u) * BO + bo;
                h[ps][u] = out[idx];
                l[ps][u] = (float)lo[idx];
            }
        }
#pragma unroll
        for (int u = 0; u < 4; ++u) {
            const double du = (double)h[cs][u] + (double)l[cs][u] * 0x1p-12;
            m += du;
            const double s = (m > 15.0) ? 1.0 : 0.0;
            m = fmin(fmax(m, 0.0), 15.0);
            out[(size_t)(g * 4 + u) * BO + bo] = (float)s;
            cnt += s;
            m -= m * s;
        }
    }
    out[(size_t)T_STEPS * BO + bo] = (float)m;
    out[(size_t)(T_STEPS + 1) * BO + bo] = (float)(cnt * 0.01);
}

extern "C" void kernel_launch(void* const* d_in, const int* in_sizes, int n_in,
                              void* d_out, int out_size, void* d_ws, size_t ws_size,
                              hipStream_t stream) {
    const float* spikes = (const float*)d_in[0];  // [100,64,1024]
    const float* mem    = (const float*)d_in[1];  // [64,1024]
    // d_in[2] = hat_spikes: dead in forward
    const float* W      = (const float*)d_in[3];  // [1024,1024]
    const float* b      = (const float*)d_in[4];  // [1024]
    float* out = (float*)d_out;
    signed char* A8 = (signed char*)d_ws + A8_OFF;
    signed char* Bt = (signed char*)d_ws + BT_OFF;
    _Float16*    Lo = (_Float16*)((char*)d_ws + LO_OFF);

    prepass<<<dim3(1856), 256, 0, stream>>>(spikes, W, A8, Bt);
    gemm_i8<<<dim3(32, 100), 256, 0, stream>>>(A8, Bt, b, out, Lo);
    snn_scan<<<dim3(BO / 256), 256, 0, stream>>>(out, Lo, mem);
}

// Round 16
// 143.698 us; speedup vs baseline: 1.3092x; 1.1269x over previous
//
#include <hip/hip_runtime.h>

// SNNLinear, exact-trajectory i8-digit MFMA. Round 16 = R13 with the W
// decomposition cut from 5 planes (scale 2^36) to 4 planes (scale 2^28):
//   - |Wq|=|round(W*2^28)| < 2^30.5 fits 4 balanced base-256 i8 digits
//     (measured max|W|~5.2; overflow needs |W|>8, P~1e-9).
//   - du quant error std ~2.4e-8 (worst 9.5e-7): expected spike flips vs
//     f64 trajectory ~0.02 across 6.5M samples -> ~98% identical; accepted.
//   - 20% fewer MFMA + 20% less B traffic (L2-port-bound per R8/R11/R15
//     triangulation) + acc 80->64 regs -> 3 waves/SIMD via launch_bounds.
// Everything else R13 verbatim (tile 128m x 32n, XCD swizzle, 2-deep
// pipeline, fragment-coalesced prepass, f64 scan).
// Outputs: ss[100,64,1024] | mem_out[64,1024] | hat_s[64,1024]
// ws: [0,6.55M) A8 ; [6.55M,10.7M) Bt(4pl) ; [11.8M,24.9M) Lo

typedef __attribute__((ext_vector_type(4))) int int4v;

#define T_STEPS 100
#define BO 65536
#define K_DIM 1024
#define A8_OFF 0
#define BT_OFF 6553600
#define LO_OFF 11796480

// ---- prepass, fragment-coalesced: wave = one (m16|n16, k64) tile ----
__global__ __launch_bounds__(256)
void prepass(const float* __restrict__ S, const float* __restrict__ W,
             signed char* __restrict__ A8, signed char* __restrict__ Bt) {
    const int wave = blockIdx.x * 4 + (threadIdx.x >> 6);  // 0..7423
    const int lane = threadIdx.x & 63;
    const int r16 = lane & 15, quad = lane >> 4;

    if (wave < 6400) {
        // spikes -> A8: tile (m16, k64); lane writes frag slot lane.
        const int m16 = wave >> 4, k64 = wave & 15;
        const int m = m16 * 16 + r16;
        const float* sp = S + (size_t)m * K_DIM + k64 * 64 + quad * 16;
        const float4 s0 = *(const float4*)(sp);
        const float4 s1 = *(const float4*)(sp + 4);
        const float4 s2 = *(const float4*)(sp + 8);
        const float4 s3 = *(const float4*)(sp + 12);
        const float sv[16] = {s0.x,s0.y,s0.z,s0.w, s1.x,s1.y,s1.z,s1.w,
                              s2.x,s2.y,s2.z,s2.w, s3.x,s3.y,s3.z,s3.w};
        union { signed char c[16]; int4v v; } u;
#pragma unroll
        for (int e = 0; e < 16; ++e) u.c[e] = (signed char)sv[e];   // exact 0/1
        *(int4v*)(A8 + ((size_t)(m16 * 16 + k64) * 1024) + lane * 16) = u.v;
    } else {
        // W -> Bt: 4 balanced base-256 digit planes at scale 2^28.
        const int t2 = wave - 6400;                 // 0..1023
        const int n16 = t2 >> 4, k64 = t2 & 15;
        const int n = n16 * 16 + r16;
        const float* wp = W + (size_t)n * K_DIM + k64 * 64 + quad * 16;
        const float4 w0 = *(const float4*)(wp);
        const float4 w1 = *(const float4*)(wp + 4);
        const float4 w2 = *(const float4*)(wp + 8);
        const float4 w3 = *(const float4*)(wp + 12);
        const float wv[16] = {w0.x,w0.y,w0.z,w0.w, w1.x,w1.y,w1.z,w1.w,
                              w2.x,w2.y,w2.z,w2.w, w3.x,w3.y,w3.z,w3.w};
        union { signed char c[16]; int4v v; } u[4];
#pragma unroll
        for (int e = 0; e < 16; ++e) {
            long long q = llrint((double)wv[e] * 0x1p28);   // |q| < 2^31
#pragma unroll
            for (int p = 0; p < 3; ++p) {
                const int d = (int)(((q + 128) & 255) - 128);  // [-128,127]
                u[p].c[e] = (signed char)d;
                q = (q - d) >> 8;                              // exact
            }
            u[3].c[e] = (signed char)q;                        // |d3| <= ~83
        }
        signed char* base = Bt + (size_t)(n16 * 16 + k64) * 4 * 1024 + lane * 16;
#pragma unroll
        for (int p = 0; p < 4; ++p)
            *(int4v*)(base + (size_t)p * 1024) = u[p].v;
    }
}

// ---- GEMM: block 128m x 32n = 4 waves (2m x 2n), wave 64m x 16n x 4 planes.
// No LDS/barriers; 2-deep register pipeline; 3 waves/SIMD. ----
__global__ __launch_bounds__(256, 3)
void gemm_i8(const signed char* __restrict__ A8,
             const signed char* __restrict__ Bt,
             const float* __restrict__ bias,
             float* __restrict__ Chi,          // hi -> ss region
             _Float16* __restrict__ Lo) {      // lo*4096 residual
    const int bid = blockIdx.x;                // 0..1599
    const int xcd = bid & 7;
    const int t_  = bid >> 3;
    const int cu  = t_ & 31;
    const int rnd = t_ >> 5;
    const int bn = (xcd << 2) | (cu & 3);      // 0..31
    const int bm = (cu >> 2) + (rnd << 3);     // 0..49

    const int tid = threadIdx.x;
    const int lane = tid & 63, wid = tid >> 6;
    const int wm = wid >> 1, wn = wid & 1;
    const int quad = lane >> 4, r16 = lane & 15;
    const int mgb = bm * 8 + wm * 4;
    const int ng  = bn * 2 + wn;

    const signed char* Ab = A8 + (size_t)mgb * 16384 + (size_t)lane * 16;
    const signed char* Bb = Bt + (size_t)ng * 65536 + (size_t)lane * 16;

    int4v a0[4], a1[4], b0[4], b1[4];
    int4v acc[4][4] = {};

    auto loadA = [&](int kt, int4v* a) {
#pragma unroll
        for (int i = 0; i < 4; ++i)
            a[i] = *(const int4v*)(Ab + (size_t)(i * 16 + kt) * 1024);
    };
    auto loadB = [&](int kt, int4v* b) {
#pragma unroll
        for (int p = 0; p < 4; ++p)
            b[p] = *(const int4v*)(Bb + (size_t)(kt * 4 + p) * 1024);
    };
    auto mf = [&](const int4v* a, const int4v* b) {
#pragma unroll
        for (int p = 0; p < 4; ++p)
#pragma unroll
            for (int i = 0; i < 4; ++i)
                acc[i][p] = __builtin_amdgcn_mfma_i32_16x16x64_i8(
                    a[i], b[p], acc[i][p], 0, 0, 0);
    };

    loadA(0, a0); loadB(0, b0);
    loadA(1, a1); loadB(1, b1);
    for (int kt = 0; kt < 16; kt += 2) {
        mf(a0, b0);
        if (kt + 2 < 16) { loadA(kt + 2, a0); loadB(kt + 2, b0); }
        mf(a1, b1);
        if (kt + 3 < 16) { loadA(kt + 3, a1); loadB(kt + 3, b1); }
    }

    // epilogue: exact i64 Horner recombine -> f64 du -> hi/lo store
    const int n_g = bn * 32 + wn * 16 + r16;
    const double bd = (double)bias[n_g];
#pragma unroll
    for (int i = 0; i < 4; ++i)
#pragma unroll
        for (int e = 0; e < 4; ++e) {
            long long t = (long long)acc[i][3][e];
            t = t * 256 + (long long)acc[i][2][e];
            t = t * 256 + (long long)acc[i][1][e];
            t = t * 256 + (long long)acc[i][0][e];   // exact, |t| < 2^42
            const double du = (double)t * 0x1p-28 + bd;
            const float hi = (float)du;
            const float lo = (float)(du - (double)hi);
            const size_t m_g = (size_t)(bm * 128 + wm * 64 + i * 16 + quad * 4 + e);
            const size_t off = m_g * 1024 + n_g;
            Chi[off] = hi;
            Lo[off] = (_Float16)(lo * 4096.0f);
        }
}

// ---- membrane scan (R13 verbatim): f64, 4-slot ring, 3 groups ahead ----
__global__ __launch_bounds__(256)
void snn_scan(float* __restrict__ out, const _Float16* __restrict__ lo,
              const float* __restrict__ mem0) {
    const int bo = blockIdx.x * 256 + threadIdx.x;
    double m = (double)mem0[bo];
    double cnt = 0.0;
    float h[4][4], l[4][4];
#pragma unroll
    for (int s = 0; s < 3; ++s)
#pragma unroll
        for (int u = 0; u < 4; ++u) {
            const size_t idx = (size_t)(s * 4 + u) * BO + bo;
            h[s][u] = out[idx];
            l[s][u] = (float)lo[idx];
        }
#pragma unroll
    for (int g = 0; g < 25; ++g) {
        const int cs = g & 3, ps = (g + 3) & 3;
        if (g + 3 < 25) {
#pragma unroll
            for (int u = 0; u < 4; ++u) {
                const size_t idx = (size_t)((g + 3) * 4 + u) * BO + bo;
                h[ps][u] = out[idx];
                l[ps][u] = (float)lo[idx];
            }
        }
#pragma unroll
        for (int u = 0; u < 4; ++u) {
            const double du = (double)h[cs][u] + (double)l[cs][u] * 0x1p-12;
            m += du;
            const double s = (m > 15.0) ? 1.0 : 0.0;
            m = fmin(fmax(m, 0.0), 15.0);
            out[(size_t)(g * 4 + u) * BO + bo] = (float)s;
            cnt += s;
            m -= m * s;
        }
    }
    out[(size_t)T_STEPS * BO + bo] = (float)m;
    out[(size_t)(T_STEPS + 1) * BO + bo] = (float)(cnt * 0.01);
}

extern "C" void kernel_launch(void* const* d_in, const int* in_sizes, int n_in,
                              void* d_out, int out_size, void* d_ws, size_t ws_size,
                              hipStream_t stream) {
    const float* spikes = (const float*)d_in[0];  // [100,64,1024]
    const float* mem    = (const float*)d_in[1];  // [64,1024]
    // d_in[2] = hat_spikes: dead in forward
    const float* W      = (const float*)d_in[3];  // [1024,1024]
    const float* b      = (const float*)d_in[4];  // [1024]
    float* out = (float*)d_out;
    signed char* A8 = (signed char*)d_ws + A8_OFF;
    signed char* Bt = (signed char*)d_ws + BT_OFF;
    _Float16*    Lo = (_Float16*)((char*)d_ws + LO_OFF);

    prepass<<<dim3(1856), 256, 0, stream>>>(spikes, W, A8, Bt);
    gemm_i8<<<dim3(1600), 256, 0, stream>>>(A8, Bt, b, out, Lo);
    snn_scan<<<dim3(BO / 256), 256, 0, stream>>>(out, Lo, mem);
}

// Round 17
// 138.773 us; speedup vs baseline: 1.3557x; 1.0355x over previous
//
#include <hip/hip_runtime.h>

// SNNLinear, exact-trajectory i8-digit MFMA. Round 17 = R16 with the GEMM
// K-loop pipeline deepened: 3-slot register ring, loads for kt+2 issued
// BEFORE consuming kt (in-flight cover ~2 MFMA phases ~500 cyc vs L2/LLC
// ~200-400) at the cost of +32 regs (~184 -> 2 waves/SIMD). Direct A/B test
// vs R16 (depth-1, 3 waves/SIMD) with bytes/MAC held fixed.
// Math bit-identical to R16: Wq=round(W*2^28), 4 balanced base-256 i8
// planes; mfma_i32_16x16x64_i8 exact; i64 Horner -> f64 du -> f32 hi
// (ss region) + f16 lo*2^12 (ws). Scan f64.
// Outputs: ss[100,64,1024] | mem_out[64,1024] | hat_s[64,1024]
// ws: [0,6.55M) A8 ; [6.55M,10.7M) Bt(4pl) ; [11.8M,24.9M) Lo

typedef __attribute__((ext_vector_type(4))) int int4v;

#define T_STEPS 100
#define BO 65536
#define K_DIM 1024
#define A8_OFF 0
#define BT_OFF 6553600
#define LO_OFF 11796480

// ---- prepass (R16 verbatim), fragment-coalesced ----
__global__ __launch_bounds__(256)
void prepass(const float* __restrict__ S, const float* __restrict__ W,
             signed char* __restrict__ A8, signed char* __restrict__ Bt) {
    const int wave = blockIdx.x * 4 + (threadIdx.x >> 6);  // 0..7423
    const int lane = threadIdx.x & 63;
    const int r16 = lane & 15, quad = lane >> 4;

    if (wave < 6400) {
        const int m16 = wave >> 4, k64 = wave & 15;
        const int m = m16 * 16 + r16;
        const float* sp = S + (size_t)m * K_DIM + k64 * 64 + quad * 16;
        const float4 s0 = *(const float4*)(sp);
        const float4 s1 = *(const float4*)(sp + 4);
        const float4 s2 = *(const float4*)(sp + 8);
        const float4 s3 = *(const float4*)(sp + 12);
        const float sv[16] = {s0.x,s0.y,s0.z,s0.w, s1.x,s1.y,s1.z,s1.w,
                              s2.x,s2.y,s2.z,s2.w, s3.x,s3.y,s3.z,s3.w};
        union { signed char c[16]; int4v v; } u;
#pragma unroll
        for (int e = 0; e < 16; ++e) u.c[e] = (signed char)sv[e];   // exact 0/1
        *(int4v*)(A8 + ((size_t)(m16 * 16 + k64) * 1024) + lane * 16) = u.v;
    } else {
        const int t2 = wave - 6400;                 // 0..1023
        const int n16 = t2 >> 4, k64 = t2 & 15;
        const int n = n16 * 16 + r16;
        const float* wp = W + (size_t)n * K_DIM + k64 * 64 + quad * 16;
        const float4 w0 = *(const float4*)(wp);
        const float4 w1 = *(const float4*)(wp + 4);
        const float4 w2 = *(const float4*)(wp + 8);
        const float4 w3 = *(const float4*)(wp + 12);
        const float wv[16] = {w0.x,w0.y,w0.z,w0.w, w1.x,w1.y,w1.z,w1.w,
                              w2.x,w2.y,w2.z,w2.w, w3.x,w3.y,w3.z,w3.w};
        union { signed char c[16]; int4v v; } u[4];
#pragma unroll
        for (int e = 0; e < 16; ++e) {
            long long q = llrint((double)wv[e] * 0x1p28);   // |q| < 2^31
#pragma unroll
            for (int p = 0; p < 3; ++p) {
                const int d = (int)(((q + 128) & 255) - 128);  // [-128,127]
                u[p].c[e] = (signed char)d;
                q = (q - d) >> 8;                              // exact
            }
            u[3].c[e] = (signed char)q;                        // |d3| <= ~83
        }
        signed char* base = Bt + (size_t)(n16 * 16 + k64) * 4 * 1024 + lane * 16;
#pragma unroll
        for (int p = 0; p < 4; ++p)
            *(int4v*)(base + (size_t)p * 1024) = u[p].v;
    }
}

// ---- GEMM: block 128m x 32n = 4 waves (2m x 2n), wave 64m x 16n x 4 planes.
// No LDS/barriers; 3-slot register ring, 2-phase-ahead prefetch. ----
__global__ __launch_bounds__(256)
void gemm_i8(const signed char* __restrict__ A8,
             const signed char* __restrict__ Bt,
             const float* __restrict__ bias,
             float* __restrict__ Chi,          // hi -> ss region
             _Float16* __restrict__ Lo) {      // lo*4096 residual
    const int bid = blockIdx.x;                // 0..1599
    const int xcd = bid & 7;
    const int t_  = bid >> 3;
    const int cu  = t_ & 31;
    const int rnd = t_ >> 5;
    const int bn = (xcd << 2) | (cu & 3);      // 0..31
    const int bm = (cu >> 2) + (rnd << 3);     // 0..49

    const int tid = threadIdx.x;
    const int lane = tid & 63, wid = tid >> 6;
    const int wm = wid >> 1, wn = wid & 1;
    const int quad = lane >> 4, r16 = lane & 15;
    const int mgb = bm * 8 + wm * 4;
    const int ng  = bn * 2 + wn;

    const signed char* Ab = A8 + (size_t)mgb * 16384 + (size_t)lane * 16;
    const signed char* Bb = Bt + (size_t)ng * 65536 + (size_t)lane * 16;

    int4v av[3][4], bv[3][4];
    int4v acc[4][4] = {};

    auto loadS = [&](int kt, int s) {
#pragma unroll
        for (int i = 0; i < 4; ++i)
            av[s][i] = *(const int4v*)(Ab + (size_t)(i * 16 + kt) * 1024);
#pragma unroll
        for (int p = 0; p < 4; ++p)
            bv[s][p] = *(const int4v*)(Bb + (size_t)(kt * 4 + p) * 1024);
    };
    auto mf = [&](int s) {
#pragma unroll
        for (int p = 0; p < 4; ++p)
#pragma unroll
            for (int i = 0; i < 4; ++i)
                acc[i][p] = __builtin_amdgcn_mfma_i32_16x16x64_i8(
                    av[s][i], bv[s][p], acc[i][p], 0, 0, 0);
    };

    loadS(0, 0);
    loadS(1, 1);
#pragma unroll
    for (int kt = 0; kt < 16; ++kt) {
        if (kt + 2 < 16) loadS(kt + 2, (kt + 2) % 3);  // issue BEFORE consume
        mf(kt % 3);
    }

    // epilogue: exact i64 Horner recombine -> f64 du -> hi/lo store
    const int n_g = bn * 32 + wn * 16 + r16;
    const double bd = (double)bias[n_g];
#pragma unroll
    for (int i = 0; i < 4; ++i)
#pragma unroll
        for (int e = 0; e < 4; ++e) {
            long long t = (long long)acc[i][3][e];
            t = t * 256 + (long long)acc[i][2][e];
            t = t * 256 + (long long)acc[i][1][e];
            t = t * 256 + (long long)acc[i][0][e];   // exact, |t| < 2^42
            const double du = (double)t * 0x1p-28 + bd;
            const float hi = (float)du;
            const float lo = (float)(du - (double)hi);
            const size_t m_g = (size_t)(bm * 128 + wm * 64 + i * 16 + quad * 4 + e);
            const size_t off = m_g * 1024 + n_g;
            Chi[off] = hi;
            Lo[off] = (_Float16)(lo * 4096.0f);
        }
}

// ---- membrane scan (R16 verbatim): f64, 4-slot ring, 3 groups ahead ----
__global__ __launch_bounds__(256)
void snn_scan(float* __restrict__ out, const _Float16* __restrict__ lo,
              const float* __restrict__ mem0) {
    const int bo = blockIdx.x * 256 + threadIdx.x;
    double m = (double)mem0[bo];
    double cnt = 0.0;
    float h[4][4], l[4][4];
#pragma unroll
    for (int s = 0; s < 3; ++s)
#pragma unroll
        for (int u = 0; u < 4; ++u) {
            const size_t idx = (size_t)(s * 4 + u) * BO + bo;
            h[s][u] = out[idx];
            l[s][u] = (float)lo[idx];
        }
#pragma unroll
    for (int g = 0; g < 25; ++g) {
        const int cs = g & 3, ps = (g + 3) & 3;
        if (g + 3 < 25) {
#pragma unroll
            for (int u = 0; u < 4; ++u) {
                const size_t idx = (size_t)((g + 3) * 4 + u) * BO + bo;
                h[ps][u] = out[idx];
                l[ps][u] = (float)lo[idx];
            }
        }
#pragma unroll
        for (int u = 0; u < 4; ++u) {
            const double du = (double)h[cs][u] + (double)l[cs][u] * 0x1p-12;
            m += du;
            const double s = (m > 15.0) ? 1.0 : 0.0;
            m = fmin(fmax(m, 0.0), 15.0);
            out[(size_t)(g * 4 + u) * BO + bo] = (float)s;
            cnt += s;
            m -= m * s;
        }
    }
    out[(size_t)T_STEPS * BO + bo] = (float)m;
    out[(size_t)(T_STEPS + 1) * BO + bo] = (float)(cnt * 0.01);
}

extern "C" void kernel_launch(void* const* d_in, const int* in_sizes, int n_in,
                              void* d_out, int out_size, void* d_ws, size_t ws_size,
                              hipStream_t stream) {
    const float* spikes = (const float*)d_in[0];  // [100,64,1024]
    const float* mem    = (const float*)d_in[1];  // [64,1024]
    // d_in[2] = hat_spikes: dead in forward
    const float* W      = (const float*)d_in[3];  // [1024,1024]
    const float* b      = (const float*)d_in[4];  // [1024]
    float* out = (float*)d_out;
    signed char* A8 = (signed char*)d_ws + A8_OFF;
    signed char* Bt = (signed char*)d_ws + BT_OFF;
    _Float16*    Lo = (_Float16*)((char*)d_ws + LO_OFF);

    prepass<<<dim3(1856), 256, 0, stream>>>(spikes, W, A8, Bt);
    gemm_i8<<<dim3(1600), 256, 0, stream>>>(A8, Bt, b, out, Lo);
    snn_scan<<<dim3(BO / 256), 256, 0, stream>>>(out, Lo, mem);
}

// Round 18
// 127.712 us; speedup vs baseline: 1.4731x; 1.0866x over previous
//
#include <hip/hip_runtime.h>

// SNNLinear, exact-trajectory i8-digit MFMA. Round 18 = R16 with the GEMM
// restructured for BLOCK-LEVEL traffic dedup via LDS:
//   - per kt the block needs 16 KB (8 A-chunks, 8 B-chunks of 1 KB); in
//     R16 each of 4 waves streamed 8 KB itself -> 32 KB/blk/kt from L2.
//     Now wave w stages chunks 4w..4w+3 ONCE (global->VGPR one kt ahead,
//     ds_write after MFMA), halving L2->CU traffic 820->410 MB (~24->12us
//     of port time vs 13.6us MFMA floor).
//   - fragment layout is lane-linear 16B/lane -> ds_write_b128/ds_read_b128
//     both perfectly contiguous, zero bank conflicts (unlike R3/R5).
//   - double-buffered 16KB LDS, 1 barrier/kt, 3 blocks/CU co-resident.
// Math bit-identical to R16: Wq=round(W*2^28), 4 balanced base-256 i8
// planes; mfma_i32_16x16x64_i8 exact; i64 Horner -> f64 du -> f32 hi
// (ss region) + f16 lo*2^12 (ws). Scan f64 (R16 verbatim).
// Outputs: ss[100,64,1024] | mem_out[64,1024] | hat_s[64,1024]
// ws: [0,6.55M) A8 ; [6.55M,10.7M) Bt(4pl) ; [11.8M,24.9M) Lo

typedef __attribute__((ext_vector_type(4))) int int4v;

#define T_STEPS 100
#define BO 65536
#define K_DIM 1024
#define A8_OFF 0
#define BT_OFF 6553600
#define LO_OFF 11796480

// ---- prepass (R16 verbatim), fragment-coalesced ----
__global__ __launch_bounds__(256)
void prepass(const float* __restrict__ S, const float* __restrict__ W,
             signed char* __restrict__ A8, signed char* __restrict__ Bt) {
    const int wave = blockIdx.x * 4 + (threadIdx.x >> 6);  // 0..7423
    const int lane = threadIdx.x & 63;
    const int r16 = lane & 15, quad = lane >> 4;

    if (wave < 6400) {
        const int m16 = wave >> 4, k64 = wave & 15;
        const int m = m16 * 16 + r16;
        const float* sp = S + (size_t)m * K_DIM + k64 * 64 + quad * 16;
        const float4 s0 = *(const float4*)(sp);
        const float4 s1 = *(const float4*)(sp + 4);
        const float4 s2 = *(const float4*)(sp + 8);
        const float4 s3 = *(const float4*)(sp + 12);
        const float sv[16] = {s0.x,s0.y,s0.z,s0.w, s1.x,s1.y,s1.z,s1.w,
                              s2.x,s2.y,s2.z,s2.w, s3.x,s3.y,s3.z,s3.w};
        union { signed char c[16]; int4v v; } u;
#pragma unroll
        for (int e = 0; e < 16; ++e) u.c[e] = (signed char)sv[e];   // exact 0/1
        *(int4v*)(A8 + ((size_t)(m16 * 16 + k64) * 1024) + lane * 16) = u.v;
    } else {
        const int t2 = wave - 6400;                 // 0..1023
        const int n16 = t2 >> 4, k64 = t2 & 15;
        const int n = n16 * 16 + r16;
        const float* wp = W + (size_t)n * K_DIM + k64 * 64 + quad * 16;
        const float4 w0 = *(const float4*)(wp);
        const float4 w1 = *(const float4*)(wp + 4);
        const float4 w2 = *(const float4*)(wp + 8);
        const float4 w3 = *(const float4*)(wp + 12);
        const float wv[16] = {w0.x,w0.y,w0.z,w0.w, w1.x,w1.y,w1.z,w1.w,
                              w2.x,w2.y,w2.z,w2.w, w3.x,w3.y,w3.z,w3.w};
        union { signed char c[16]; int4v v; } u[4];
#pragma unroll
        for (int e = 0; e < 16; ++e) {
            long long q = llrint((double)wv[e] * 0x1p28);   // |q| < 2^31
#pragma unroll
            for (int p = 0; p < 3; ++p) {
                const int d = (int)(((q + 128) & 255) - 128);  // [-128,127]
                u[p].c[e] = (signed char)d;
                q = (q - d) >> 8;                              // exact
            }
            u[3].c[e] = (signed char)q;                        // |d3| <= ~83
        }
        signed char* base = Bt + (size_t)(n16 * 16 + k64) * 4 * 1024 + lane * 16;
#pragma unroll
        for (int p = 0; p < 4; ++p)
            *(int4v*)(base + (size_t)p * 1024) = u[p].v;
    }
}

// ---- GEMM: block 128m x 32n, 4 waves (2m x 2n), wave 64m x 16n x 4 planes.
// LDS block-dedup staging, double-buffered, 1 barrier/kt. ----
__global__ __launch_bounds__(256, 3)
void gemm_i8(const signed char* __restrict__ A8,
             const signed char* __restrict__ Bt,
             const float* __restrict__ bias,
             float* __restrict__ Chi,          // hi -> ss region
             _Float16* __restrict__ Lo) {      // lo*4096 residual
    __shared__ signed char lds[2][16384];      // [buf][8KB A | 8KB B]
    const int bid = blockIdx.x;                // 0..1599
    const int xcd = bid & 7;
    const int t_  = bid >> 3;
    const int cu  = t_ & 31;
    const int rnd = t_ >> 5;
    const int bn = (xcd << 2) | (cu & 3);      // 0..31
    const int bm = (cu >> 2) + (rnd << 3);     // 0..49

    const int tid = threadIdx.x;
    const int lane = tid & 63, wid = tid >> 6;
    const int wm = wid >> 1, wn = wid & 1;
    const int quad = lane >> 4, r16 = lane & 15;

    // staging assignment: wave wid stages chunks 4*wid .. 4*wid+3
    const signed char* sbase[4];
    int sstride[4], ldsoff[4];
#pragma unroll
    for (int j = 0; j < 4; ++j) {
        const int c = wid * 4 + j;             // wave-uniform
        if (c < 8) {                           // A chunk, m16 group c
            sbase[j] = A8 + (size_t)(bm * 8 + c) * 16384 + lane * 16;
            sstride[j] = 1024;
            ldsoff[j] = c * 1024 + lane * 16;
        } else {                               // B chunk: ng_loc = (c-8)>>2, plane (c-8)&3
            const int j2 = c - 8;
            sbase[j] = Bt + (size_t)(bn * 2 + (j2 >> 2)) * 65536
                          + (size_t)(j2 & 3) * 1024 + lane * 16;
            sstride[j] = 4096;
            ldsoff[j] = 8192 + j2 * 1024 + lane * 16;
        }
    }
    // fragment read offsets (lane-linear -> conflict-free b128)
    int aoff[4], boff[4];
#pragma unroll
    for (int i = 0; i < 4; ++i) aoff[i] = (wm * 4 + i) * 1024 + lane * 16;
#pragma unroll
    for (int p = 0; p < 4; ++p) boff[p] = 8192 + (wn * 4 + p) * 1024 + lane * 16;

    int4v sreg[4];
    int4v acc[4][4] = {};

    // prologue: stage kt=0 into buf0
#pragma unroll
    for (int j = 0; j < 4; ++j) sreg[j] = *(const int4v*)(sbase[j]);
#pragma unroll
    for (int j = 0; j < 4; ++j) *(int4v*)(&lds[0][ldsoff[j]]) = sreg[j];
    __syncthreads();

    for (int kt = 0; kt < 16; ++kt) {
        const int cur = kt & 1, nxt = cur ^ 1;
        if (kt + 1 < 16) {                     // global loads in flight over MFMA
#pragma unroll
            for (int j = 0; j < 4; ++j)
                sreg[j] = *(const int4v*)(sbase[j] + (size_t)(kt + 1) * sstride[j]);
        }
        int4v af[4], bf[4];
#pragma unroll
        for (int i = 0; i < 4; ++i) af[i] = *(const int4v*)(&lds[cur][aoff[i]]);
#pragma unroll
        for (int p = 0; p < 4; ++p) bf[p] = *(const int4v*)(&lds[cur][boff[p]]);
#pragma unroll
        for (int p = 0; p < 4; ++p)
#pragma unroll
            for (int i = 0; i < 4; ++i)
                acc[i][p] = __builtin_amdgcn_mfma_i32_16x16x64_i8(
                    af[i], bf[p], acc[i][p], 0, 0, 0);
        if (kt + 1 < 16) {
#pragma unroll
            for (int j = 0; j < 4; ++j) *(int4v*)(&lds[nxt][ldsoff[j]]) = sreg[j];
        }
        __syncthreads();
    }

    // epilogue (R16 verbatim): exact i64 Horner -> f64 du -> hi/lo store
    const int n_g = bn * 32 + wn * 16 + r16;
    const double bd = (double)bias[n_g];
#pragma unroll
    for (int i = 0; i < 4; ++i)
#pragma unroll
        for (int e = 0; e < 4; ++e) {
            long long t = (long long)acc[i][3][e];
            t = t * 256 + (long long)acc[i][2][e];
            t = t * 256 + (long long)acc[i][1][e];
            t = t * 256 + (long long)acc[i][0][e];   // exact, |t| < 2^42
            const double du = (double)t * 0x1p-28 + bd;
            const float hi = (float)du;
            const float lo = (float)(du - (double)hi);
            const size_t m_g = (size_t)(bm * 128 + wm * 64 + i * 16 + quad * 4 + e);
            const size_t off = m_g * 1024 + n_g;
            Chi[off] = hi;
            Lo[off] = (_Float16)(lo * 4096.0f);
        }
}

// ---- membrane scan (R16 verbatim): f64, 4-slot ring, 3 groups ahead ----
__global__ __launch_bounds__(256)
void snn_scan(float* __restrict__ out, const _Float16* __restrict__ lo,
              const float* __restrict__ mem0) {
    const int bo = blockIdx.x * 256 + threadIdx.x;
    double m = (double)mem0[bo];
    double cnt = 0.0;
    float h[4][4], l[4][4];
#pragma unroll
    for (int s = 0; s < 3; ++s)
#pragma unroll
        for (int u = 0; u < 4; ++u) {
            const size_t idx = (size_t)(s * 4 + u) * BO + bo;
            h[s][u] = out[idx];
            l[s][u] = (float)lo[idx];
        }
#pragma unroll
    for (int g = 0; g < 25; ++g) {
        const int cs = g & 3, ps = (g + 3) & 3;
        if (g + 3 < 25) {
#pragma unroll
            for (int u = 0; u < 4; ++u) {
                const size_t idx = (size_t)((g + 3) * 4 + u) * BO + bo;
                h[ps][u] = out[idx];
                l[ps][u] = (float)lo[idx];
            }
        }
#pragma unroll
        for (int u = 0; u < 4; ++u) {
            const double du = (double)h[cs][u] + (double)l[cs][u] * 0x1p-12;
            m += du;
            const double s = (m > 15.0) ? 1.0 : 0.0;
            m = fmin(fmax(m, 0.0), 15.0);
            out[(size_t)(g * 4 + u) * BO + bo] = (float)s;
            cnt += s;
            m -= m * s;
        }
    }
    out[(size_t)T_STEPS * BO + bo] = (float)m;
    out[(size_t)(T_STEPS + 1) * BO + bo] = (float)(cnt * 0.01);
}

extern "C" void kernel_launch(void* const* d_in, const int* in_sizes, int n_in,
                              void* d_out, int out_size, void* d_ws, size_t ws_size,
                              hipStream_t stream) {
    const float* spikes = (const float*)d_in[0];  // [100,64,1024]
    const float* mem    = (const float*)d_in[1];  // [64,1024]
    // d_in[2] = hat_spikes: dead in forward
    const float* W      = (const float*)d_in[3];  // [1024,1024]
    const float* b      = (const float*)d_in[4];  // [1024]
    float* out = (float*)d_out;
    signed char* A8 = (signed char*)d_ws + A8_OFF;
    signed char* Bt = (signed char*)d_ws + BT_OFF;
    _Float16*    Lo = (_Float16*)((char*)d_ws + LO_OFF);

    prepass<<<dim3(1856), 256, 0, stream>>>(spikes, W, A8, Bt);
    gemm_i8<<<dim3(1600), 256, 0, stream>>>(A8, Bt, b, out, Lo);
    snn_scan<<<dim3(BO / 256), 256, 0, stream>>>(out, Lo, mem);
}